// Round 6
// baseline (3428.577 us; speedup 1.0000x reference)
//
#include <hip/hip_runtime.h>
#include <hip/hip_fp16.h>
#include <math.h>

typedef _Float16 half8 __attribute__((ext_vector_type(8)));
typedef float f32x4 __attribute__((ext_vector_type(4)));

#define W0F 0.09817477042468103f   // 2*pi/64

__device__ __forceinline__ float sigf(float x){ return 1.f/(1.f+expf(-x)); }
__device__ __forceinline__ float lrelu(float x){ return (x>0.f)? x : 0.01f*x; }

__device__ __forceinline__ uint32_t packhl(float x){
  __half h = __float2half(x);
  __half l = __float2half(x - __half2float(h));
  return (uint32_t)__half_as_ushort(h) | ((uint32_t)__half_as_ushort(l) << 16);
}

__device__ __forceinline__ void unpackA(const uint4 d0, const uint4 d1, half8& hi, half8& lo){
  union { half8 h; uint32_t u[4]; } H, L;
  H.u[0] = (d0.x & 0xffffu) | (d0.y << 16);
  H.u[1] = (d0.z & 0xffffu) | (d0.w << 16);
  H.u[2] = (d1.x & 0xffffu) | (d1.y << 16);
  H.u[3] = (d1.z & 0xffffu) | (d1.w << 16);
  L.u[0] = (d0.x >> 16) | (d0.y & 0xffff0000u);
  L.u[1] = (d0.z >> 16) | (d0.w & 0xffff0000u);
  L.u[2] = (d1.x >> 16) | (d1.y & 0xffff0000u);
  L.u[3] = (d1.z >> 16) | (d1.w & 0xffff0000u);
  hi = H.h; lo = L.h;
}

// decode 8 biased-uint8 bytes -> half8 of (u-128)/2  (exact: f16 mantissa trick)
__device__ __forceinline__ half8 dec8i(uint32_t vx, uint32_t vy){
  union { half8 h; uint32_t u[4]; } R;
  uint32_t t;
  t = __builtin_amdgcn_perm(0u, vx, 0x0C010C00u);
  R.u[0] = ((t & 0x00ff00ffu) << 2) | 0x58005800u;
  t = __builtin_amdgcn_perm(0u, vx, 0x0C030C02u);
  R.u[1] = ((t & 0x00ff00ffu) << 2) | 0x58005800u;
  t = __builtin_amdgcn_perm(0u, vy, 0x0C010C00u);
  R.u[2] = ((t & 0x00ff00ffu) << 2) | 0x58005800u;
  t = __builtin_amdgcn_perm(0u, vy, 0x0C030C02u);
  R.u[3] = ((t & 0x00ff00ffu) << 2) | 0x58005800u;
  const _Float16 c = (_Float16)192.0f;   // 0x5A00 per half
  half8 K = {c,c,c,c,c,c,c,c};
  return R.h - K;
}

// split-f16 3-pass fp32-accurate MFMA (aux phase A)
__device__ __forceinline__ f32x4 mfma3(half8 ah, half8 al, half8 bh, half8 bl, f32x4 c){
  c = __builtin_amdgcn_mfma_f32_16x16x32_f16(ah, bh, c, 0,0,0);
  c = __builtin_amdgcn_mfma_f32_16x16x32_f16(al, bh, c, 0,0,0);
  c = __builtin_amdgcn_mfma_f32_16x16x32_f16(ah, bl, c, 0,0,0);
  return c;
}

// ---- ws layout (BYTE offsets) ----
#define HB_WH0  0u         // 131072 B (f16 hi)
#define HB_WI1  131072u
#define HB_WH1  262144u
#define HB_FC1  393216u    // 32768 B
#define HB_TP1H 425984u    // 524288 B
#define HB_TP1L 950272u    // 524288 B (f16 lo for TP1)
#define LB_WH0  1474560u   // 65536 B (int8 lo, PAIRED: 16B covers ks,ks+1)
#define LB_WI1  1540096u
#define LB_WH1  1605632u
#define LB_FC1  1671168u   // 16384 B
#define ST_WH0  1687552u   // 512 f32 scales
#define ST_L1   1689600u   // 512 f32 (shared WI1+WH1)
#define ST_F1   1691648u   // 128 f32

__global__ __launch_bounds__(256) void convert_scales(
    const float* __restrict__ w_hh0, const float* __restrict__ w_ih1,
    const float* __restrict__ w_hh1, const float* __restrict__ fc1_w,
    uint8_t* __restrict__ wsB)
{
  int i = blockIdx.x*256 + threadIdx.x;
  if (i >= 1152) return;
  float m = 0.f;
  float* dst;
  if (i < 512){
    const float* p = w_hh0 + (size_t)i*128;
    for (int k = 0; k < 128; ++k){
      float wv = p[k];
      float r = wv - __half2float(__float2half(wv));
      m = fmaxf(m, fabsf(r));
    }
    dst = (float*)(wsB + ST_WH0) + i;
  } else if (i < 1024){
    int n = i - 512;
    const float* p1 = w_ih1 + (size_t)n*128;
    const float* p2 = w_hh1 + (size_t)n*128;
    for (int k = 0; k < 128; ++k){
      float w1 = p1[k], w2 = p2[k];
      float r1 = w1 - __half2float(__float2half(w1));
      float r2 = w2 - __half2float(__float2half(w2));
      m = fmaxf(m, fmaxf(fabsf(r1), fabsf(r2)));
    }
    dst = (float*)(wsB + ST_L1) + n;
  } else {
    int n = i - 1024;
    const float* p = fc1_w + (size_t)n*128;
    for (int k = 0; k < 128; ++k){
      float wv = p[k];
      float r = wv - __half2float(__float2half(wv));
      m = fmaxf(m, fabsf(r));
    }
    dst = (float*)(wsB + ST_F1) + n;
  }
  *dst = exp2f(ceilf(log2f(fmaxf(m, 1e-30f))));
}

__global__ __launch_bounds__(256) void convert_w(
    const float* __restrict__ w_hh0, const float* __restrict__ w_ih1,
    const float* __restrict__ w_hh1, const float* __restrict__ fc1_w,
    const float* __restrict__ tp1_w, uint8_t* __restrict__ wsB)
{
  int c = blockIdx.x*256 + threadIdx.x;   // 59392 chunks of 8 elems
  const float* src; int q, K; size_t hb, lb; const float* stab_; bool isTP1 = false;
  if      (c < 8192) { src=w_hh0; q=c;        K=128;  hb=HB_WH0; lb=LB_WH0; stab_=(const float*)(wsB+ST_WH0); }
  else if (c < 16384){ src=w_ih1; q=c-8192;   K=128;  hb=HB_WI1; lb=LB_WI1; stab_=(const float*)(wsB+ST_L1); }
  else if (c < 24576){ src=w_hh1; q=c-16384;  K=128;  hb=HB_WH1; lb=LB_WH1; stab_=(const float*)(wsB+ST_L1); }
  else if (c < 26624){ src=fc1_w; q=c-24576;  K=128;  hb=HB_FC1; lb=LB_FC1; stab_=(const float*)(wsB+ST_F1); }
  else               { src=tp1_w; q=c-26624;  K=1024; hb=HB_TP1H; lb=0; stab_=0; isTP1=true; }
  int ksb  = K >> 5;
  int lane = q & 63;
  int tks  = q >> 6;
  int tile = tks / ksb, ks = tks % ksb;
  int n = tile*16 + (lane & 15);
  int k = ks*32 + (lane >> 4)*8;
  float4 a = *(const float4*)(src + (size_t)n*K + k);
  float4 b = *(const float4*)(src + (size_t)n*K + k + 4);
  float vv[8] = {a.x,a.y,a.z,a.w,b.x,b.y,b.z,b.w};
  union { uint4 u; unsigned short s[8]; } HI;
  float hf[8];
  #pragma unroll
  for (int j = 0; j < 8; ++j){
    __half hh = __float2half(vv[j]);
    HI.s[j] = __half_as_ushort(hh);
    hf[j] = __half2float(hh);
  }
  *(uint4*)(wsB + hb + (size_t)q*16) = HI.u;
  if (isTP1){
    union { uint4 u; unsigned short s[8]; } LO;
    #pragma unroll
    for (int j = 0; j < 8; ++j)
      LO.s[j] = __half_as_ushort(__float2half(vv[j] - hf[j]));
    *(uint4*)(wsB + HB_TP1L + (size_t)q*16) = LO.u;
  } else {
    float s = stab_[n];
    float inv = 128.f / s;
    union { uint2 u; uint8_t b[8]; } L8;
    #pragma unroll
    for (int j = 0; j < 8; ++j){
      float r = (vv[j] - hf[j]) * inv;
      int qv = (int)rintf(r);
      qv = (qv < -127) ? -127 : ((qv > 127) ? 127 : qv);
      L8.b[j] = (uint8_t)(qv + 128);
    }
    // paired layout: 16B chunk p=(tile*2+ks/2)*64+lane holds [ks even 8B | ks odd 8B]
    size_t lodst = lb + (size_t)(((tile*2 + (ks>>1))*64 + lane))*16 + (size_t)(ks&1)*8;
    *(uint2*)(wsB + lodst) = L8.u;
  }
}

__global__ __launch_bounds__(512,2) void mkty_main(
    const float* __restrict__ data, const float* __restrict__ text_feature,
    const float* __restrict__ q_w, const float* __restrict__ q_b,
    const float* __restrict__ k_w, const float* __restrict__ k_b,
    const float* __restrict__ v_w, const float* __restrict__ v_b,
    const float* __restrict__ tp1_b,
    const float* __restrict__ tp2_w, const float* __restrict__ tp2_b,
    const float* __restrict__ g1_w, const float* __restrict__ g1_b,
    const float* __restrict__ g2_w, const float* __restrict__ g2_b,
    const float* __restrict__ w_ih0, const float* __restrict__ b_ih0,
    const float* __restrict__ b_hh0,
    const float* __restrict__ b_ih1, const float* __restrict__ b_hh1,
    const float* __restrict__ fc1_b,
    const float* __restrict__ fc2_w, const float* __restrict__ fc2_b,
    const uint8_t* __restrict__ wsB, float* __restrict__ out)
{
  __shared__ float s_x[32][64];
  __shared__ float s_gate[32][16];
  __shared__ float s_rec[32][16];
  __shared__ float s_res[32][16];
  __shared__ float s_pred[32];
  __shared__ float ctab[64], stab[64];
  __shared__ __align__(16) unsigned char bufBig[33792];
  __shared__ __align__(16) unsigned char bufMed[16896];

  const int tid = threadIdx.x;
  const int w = tid >> 6, l = tid & 63;
  const int lm = l & 15, lq = l >> 4;
  const int s0blk = blockIdx.x * 32;

  {
    int f=tid*4, s=f>>6, j=f&63;
    *reinterpret_cast<float4*>(&s_x[s][j]) =
      *reinterpret_cast<const float4*>(data + (size_t)(s0blk+s)*64 + j);
  }
  if (tid<64){
    float sv,cv;
    sincosf((float)tid * W0F, &sv, &cv);
    stab[tid] = (tid==32) ? 0.f : sv;
    ctab[tid] = cv;
  }
  __syncthreads();

  // ================= Phase A: h256 = lrelu(tf @ tp1_w^T + b1)  (MFMA) =================
  {
    float* h256 = (float*)bufBig;            // [32][260]
    uint32_t* tfp = (uint32_t*)bufMed;       // [32][68] packed hi/lo
    const half8* T1h = (const half8*)(wsB + HB_TP1H);
    const half8* T1l = (const half8*)(wsB + HB_TP1L);
    const int t0 = 2*w;
    f32x4 acc[2][2];
    #pragma unroll
    for (int mt=0; mt<2; ++mt)
      #pragma unroll
      for (int nt=0; nt<2; ++nt){ f32x4 z = {0.f,0.f,0.f,0.f}; acc[mt][nt] = z; }
    for (int kc = 0; kc < 1024; kc += 64){
      __syncthreads();
      { int s = tid >> 4, j0=(tid&15)*4;
        float4 v = *(const float4*)(text_feature + (size_t)(s0blk+s)*1024 + kc + j0);
        uint4 p; p.x = packhl(v.x); p.y = packhl(v.y); p.z = packhl(v.z); p.w = packhl(v.w);
        *(uint4*)&tfp[s*68 + j0] = p; }
      __syncthreads();
      #pragma unroll
      for (int ks = 0; ks < 2; ++ks){
        half8 Ah[2], Al[2];
        #pragma unroll
        for (int mt = 0; mt < 2; ++mt){
          const uint32_t* pp = &tfp[(mt*16+lm)*68 + ks*32 + lq*8];
          unpackA(*(const uint4*)pp, *(const uint4*)(pp+4), Ah[mt], Al[mt]);
        }
        int ksg = (kc >> 5) + ks;
        #pragma unroll
        for (int nt = 0; nt < 2; ++nt){
          int ci = ((t0+nt)*32 + ksg)*64 + l;
          half8 bh = T1h[ci], bl = T1l[ci];
          #pragma unroll
          for (int mt = 0; mt < 2; ++mt)
            acc[mt][nt] = mfma3(Ah[mt],Al[mt],bh,bl,acc[mt][nt]);
        }
      }
    }
    __syncthreads();
    #pragma unroll
    for (int nt = 0; nt < 2; ++nt){
      int n = (t0+nt)*16 + lm;
      float bb = tp1_b[n];
      #pragma unroll
      for (int mt = 0; mt < 2; ++mt)
        #pragma unroll
        for (int r = 0; r < 4; ++r)
          h256[(mt*16 + lq*4 + r)*260 + n] = lrelu(acc[mt][nt][r] + bb);
    }
  }
  __syncthreads();

  // ================= Phase B: tp = h256 @ tp2_w^T + b2 =================
  {
    const float* h256 = (const float*)bufBig;
    int o = tid & 127, soct = tid >> 7, ss = soct*8;
    float acc8[8];
    #pragma unroll
    for (int i=0;i<8;++i) acc8[i]=0.f;
    const float4* w2r = (const float4*)(tp2_w + o*256);
    #pragma unroll 4
    for (int k4 = 0; k4 < 64; ++k4){
      float4 w4 = w2r[k4];
      #pragma unroll
      for (int i = 0; i < 8; ++i){
        float4 hv = *(const float4*)&h256[(ss+i)*260 + k4*4];
        acc8[i] += w4.x*hv.x; acc8[i] += w4.y*hv.y;
        acc8[i] += w4.z*hv.z; acc8[i] += w4.w*hv.w;
      }
    }
    __syncthreads();
    float* tpT = (float*)bufMed;     // [32][128]
    float bb = tp2_b[o];
    #pragma unroll
    for (int i=0;i<8;++i) tpT[(ss+i)*128 + o] = acc8[i] + bb;
  }
  __syncthreads();

  // ================= Phase C: DFT -> featT[64][32] =================
  {
    float* featT = (float*)bufBig;
    #pragma unroll
    for (int i = 0; i < 2; ++i){
      int task = tid + 512*i;
      int s = task >> 5;
      int k = (task & 31) + 1;
      float re = 0.f, im = 0.f;
      #pragma unroll 8
      for (int n = 0; n < 64; ++n){
        float d = s_x[s][n];
        int m = (k*n) & 63;
        re += d*ctab[m]; im -= d*stab[m];
      }
      if (k == 32) im = 0.f;
      featT[(k-1)*32 + s] = sqrtf(re*re + im*im);
      featT[(31+k)*32 + s] = atan2f(im, re);
    }
  }
  __syncthreads();

  // ================= Phase D: Q,K,V ; QK = Q*K =================
  {
    const float* featT = (const float*)bufBig;
    const float* tpT = (const float*)bufMed;
    float* QK = (float*)(bufBig + 8192);
    float* V  = (float*)(bufBig + 16384);
    #pragma unroll
    for (int i = 0; i < 4; ++i){
      int task = tid + 512*i;
      int s = task >> 6, o = task & 63;
      float q = q_b[o];
      const float* qwr = q_w + o*64;
      #pragma unroll 4
      for (int k = 0; k < 64; ++k) q += qwr[k]*featT[k*32 + s];
      float kk = k_b[o];
      const float* kwr = k_w + o*128;
      const float* tps = tpT + s*128;
      #pragma unroll 4
      for (int k = 0; k < 128; ++k) kk += kwr[k]*tps[k];
      float vv = v_b[o];
      const float* vwr = v_w + o*128;
      #pragma unroll 4
      for (int k = 0; k < 128; ++k) vv += vwr[k]*tps[k];
      QK[s*64+o] = q*kk; V[s*64+o] = vv;
    }
  }
  __syncthreads();

  // ================= Phase E: adj = softmax(QK)*V =================
  if (tid < 32){
    float* QK = (float*)(bufBig + 8192);
    const float* V = (const float*)(bufBig + 16384);
    float mx = -1e30f;
    for (int o = 0; o < 64; ++o) mx = fmaxf(mx, QK[tid*64+o]);
    float sum = 0.f;
    for (int o = 0; o < 64; ++o){ float e = expf(QK[tid*64+o]-mx); QK[tid*64+o] = e; sum += e; }
    float inv = 1.f/sum;
    for (int o = 0; o < 64; ++o) QK[tid*64+o] *= inv*V[tid*64+o];
  }
  __syncthreads();

  // ================= Phase F: mid = lrelu(adj @ g1_w^T + b) =================
  {
    const float* ADJ = (const float*)(bufBig + 8192);
    float* midT = (float*)bufMed;    // [32][128]
    int j = tid & 127, soct = tid >> 7, ss = soct*8;
    float accm[8];
    float bb = g1_b[j];
    #pragma unroll
    for (int i=0;i<8;++i) accm[i]=bb;
    const float* wr = g1_w + j*64;
    #pragma unroll 4
    for (int k = 0; k < 64; ++k){
      float ww = wr[k];
      #pragma unroll
      for (int i=0;i<8;++i) accm[i] += ww*ADJ[(ss+i)*64 + k];
    }
    #pragma unroll
    for (int i=0;i<8;++i) midT[(ss+i)*128 + j] = lrelu(accm[i]);
  }
  __syncthreads();

  // ================= Phase G: gate + recon =================
  {
    int s = tid >> 4, o = tid & 15;
    const float* midT = (const float*)bufMed;
    const float* ADJ = (const float*)(bufBig + 8192);
    float acc = g2_b[o];
    const float* wr = g2_w + o*128;
    #pragma unroll 4
    for (int k = 0; k < 128; ++k) acc += wr[k]*midT[s*128 + k];
    float gate = sigf(acc);
    float sum = 0.f;
    float a32 = ADJ[s*64+31], p32 = ADJ[s*64+63];
    #pragma unroll
    for (int k = 1; k < 32; ++k){
      float amp = ADJ[s*64 + k-1];
      float ph  = ADJ[s*64 + 31+k];
      int m = (k*o) & 63;
      sum += amp*cosf(ph + (float)m*W0F);
    }
    float parity = (o&1)? -1.f : 1.f;
    s_gate[s][o] = gate;
    s_rec[s][o] = (2.f*sum + parity*a32*cosf(p32))*(1.f/64.f);
  }
  __syncthreads();

  // ================= LSTM (f16-hi resident WH0 + paired int8-lo MFMA) =================
  { uint32_t* hp = (uint32_t*)bufBig;
    for (int i = tid; i < 8448; i += 512) hp[i] = 0; }
  if (tid < 32) s_pred[tid] = s_x[tid][63];

  float c0[2][4] = {{0.f,0.f,0.f,0.f},{0.f,0.f,0.f,0.f}};
  float c1[2][4] = {{0.f,0.f,0.f,0.f},{0.f,0.f,0.f,0.f}};
  const int u = 16*w + lm;
  float bias0[4], wx0[4], bias1[4];
  float s0m[4], s1m[4];
  {
    const float* stW = (const float*)(wsB + ST_WH0);
    const float* stL = (const float*)(wsB + ST_L1);
    #pragma unroll
    for (int T = 0; T < 4; ++T){
      int n = T*128 + u;
      bias0[T] = b_ih0[n] + b_hh0[n];
      wx0[T]   = w_ih0[n];
      bias1[T] = b_ih1[n] + b_hh1[n];
      s0m[T] = stW[n] * 0.015625f;   // s/64
      s1m[T] = stL[n] * 0.015625f;
    }
  }
  const float fb = fc1_b[u];
  const float sfm = ((const float*)(wsB + ST_F1))[u] * 0.015625f;
  const half8* WH0h = (const half8*)(wsB + HB_WH0);
  const half8* WI1h = (const half8*)(wsB + HB_WI1);
  const half8* WH1h = (const half8*)(wsB + HB_WH1);
  const half8* F1h  = (const half8*)(wsB + HB_FC1);
  uint32_t* h0p = (uint32_t*)bufBig;             // [32][132]
  uint32_t* h1p = (uint32_t*)(bufBig + 16896);   // [32][132]
  float* midD = (float*)bufMed;                  // [32][132] f32 (decode)
  const int cbase = w*256 + l;
  const size_t pbase = (size_t)(w*128 + l);      // paired-lo base index

  // ---- WH0 f16-hi fragments: load ONCE, resident in registers for all 80 steps ----
  half8 WH0r[16];
  #pragma unroll
  for (int nt = 0; nt < 4; ++nt)
    #pragma unroll
    for (int ks = 0; ks < 4; ++ks)
      WH0r[nt*4+ks] = WH0h[nt*2048 + ks*64 + cbase];

  __syncthreads();

  for (int t = 0; t < 80; ++t){
    // ---- GEMM0: gates0 = h0 @ WH0^T + x*w_ih0 + b ----
    float xv[2][4];
    #pragma unroll
    for (int mt = 0; mt < 2; ++mt)
      #pragma unroll
      for (int r = 0; r < 4; ++r){
        int m = mt*16 + lq*4 + r;
        xv[mt][r] = (t < 64) ? s_x[m][t] : s_pred[m];
      }
    f32x4 acc0[2][4], accL[2][4];
    #pragma unroll
    for (int nt = 0; nt < 4; ++nt)
      #pragma unroll
      for (int mt = 0; mt < 2; ++mt){
        f32x4 a;
        #pragma unroll
        for (int r = 0; r < 4; ++r) a[r] = bias0[nt] + wx0[nt]*xv[mt][r];
        acc0[mt][nt] = a;
        f32x4 z = {0.f,0.f,0.f,0.f};
        accL[mt][nt] = z;
      }
    #pragma unroll
    for (int ks2 = 0; ks2 < 2; ++ks2){
      half8 Ah[2][2], Al[2][2];    // [kk][mt]
      #pragma unroll
      for (int kk = 0; kk < 2; ++kk)
        #pragma unroll
        for (int mt = 0; mt < 2; ++mt){
          const uint32_t* pp = &h0p[(mt*16+lm)*132 + (ks2*2+kk)*32 + lq*8];
          unpackA(*(const uint4*)pp, *(const uint4*)(pp+4), Ah[kk][mt], Al[kk][mt]);
        }
      #pragma unroll
      for (int nt = 0; nt < 4; ++nt){
        uint4 LV = *(const uint4*)(wsB + LB_WH0 + ((size_t)nt*1024 + (size_t)ks2*64 + pbase)*16);
        half8 blE = dec8i(LV.x, LV.y);
        half8 blO = dec8i(LV.z, LV.w);
        half8 bhE = WH0r[nt*4 + ks2*2];
        half8 bhO = WH0r[nt*4 + ks2*2 + 1];
        #pragma unroll
        for (int mt = 0; mt < 2; ++mt){
          acc0[mt][nt] = __builtin_amdgcn_mfma_f32_16x16x32_f16(Ah[0][mt], bhE, acc0[mt][nt], 0,0,0);
          acc0[mt][nt] = __builtin_amdgcn_mfma_f32_16x16x32_f16(Al[0][mt], bhE, acc0[mt][nt], 0,0,0);
          accL[mt][nt] = __builtin_amdgcn_mfma_f32_16x16x32_f16(Ah[0][mt], blE, accL[mt][nt], 0,0,0);
          acc0[mt][nt] = __builtin_amdgcn_mfma_f32_16x16x32_f16(Ah[1][mt], bhO, acc0[mt][nt], 0,0,0);
          acc0[mt][nt] = __builtin_amdgcn_mfma_f32_16x16x32_f16(Al[1][mt], bhO, acc0[mt][nt], 0,0,0);
          accL[mt][nt] = __builtin_amdgcn_mfma_f32_16x16x32_f16(Ah[1][mt], blO, accL[mt][nt], 0,0,0);
        }
      }
    }
    __syncthreads();   // S1
    #pragma unroll
    for (int mt = 0; mt < 2; ++mt)
      #pragma unroll
      for (int r = 0; r < 4; ++r){
        float gi = acc0[mt][0][r] + accL[mt][0][r]*s0m[0];
        float gf = acc0[mt][1][r] + accL[mt][1][r]*s0m[1];
        float gg = acc0[mt][2][r] + accL[mt][2][r]*s0m[2];
        float go = acc0[mt][3][r] + accL[mt][3][r]*s0m[3];
        float c = sigf(gf)*c0[mt][r] + sigf(gi)*tanhf(gg);
        float h = sigf(go)*tanhf(c);
        c0[mt][r] = c;
        h0p[(mt*16 + lq*4 + r)*132 + u] = packhl(h);
      }
    __syncthreads();   // S2
    // ---- GEMM1: gates1 = h0new @ WI1^T + h1 @ WH1^T + b ----
    f32x4 acc1[2][4], accM[2][4];
    #pragma unroll
    for (int nt = 0; nt < 4; ++nt)
      #pragma unroll
      for (int mt = 0; mt < 2; ++mt){
        f32x4 a; float bb = bias1[nt];
        a[0]=bb; a[1]=bb; a[2]=bb; a[3]=bb;
        acc1[mt][nt] = a;
        f32x4 z = {0.f,0.f,0.f,0.f};
        accM[mt][nt] = z;
      }
    #pragma unroll
    for (int ks2 = 0; ks2 < 2; ++ks2){
      half8 bo0[4], bo1[4];   // odd-ks lo frags carried from kk=0
      #pragma unroll
      for (int kk = 0; kk < 2; ++kk){
        int ks = ks2*2 + kk;
        half8 A0h[2], A0l[2], A1h[2], A1l[2];
        #pragma unroll
        for (int mt = 0; mt < 2; ++mt){
          const uint32_t* p0 = &h0p[(mt*16+lm)*132 + ks*32 + lq*8];
          unpackA(*(const uint4*)p0, *(const uint4*)(p0+4), A0h[mt], A0l[mt]);
          const uint32_t* p1 = &h1p[(mt*16+lm)*132 + ks*32 + lq*8];
          unpackA(*(const uint4*)p1, *(const uint4*)(p1+4), A1h[mt], A1l[mt]);
        }
        #pragma unroll
        for (int nt = 0; nt < 4; ++nt){
          int ci = nt*2048 + ks*64 + cbase;
          half8 bh0 = WI1h[ci];
          half8 bh1 = WH1h[ci];
          half8 bl0, bl1;
          if (kk == 0){
            uint4 LV0 = *(const uint4*)(wsB + LB_WI1 + ((size_t)nt*1024 + (size_t)ks2*64 + pbase)*16);
            uint4 LV1 = *(const uint4*)(wsB + LB_WH1 + ((size_t)nt*1024 + (size_t)ks2*64 + pbase)*16);
            bl0 = dec8i(LV0.x, LV0.y); bo0[nt] = dec8i(LV0.z, LV0.w);
            bl1 = dec8i(LV1.x, LV1.y); bo1[nt] = dec8i(LV1.z, LV1.w);
          } else { bl0 = bo0[nt]; bl1 = bo1[nt]; }
          #pragma unroll
          for (int mt = 0; mt < 2; ++mt){
            acc1[mt][nt] = __builtin_amdgcn_mfma_f32_16x16x32_f16(A0h[mt], bh0, acc1[mt][nt], 0,0,0);
            acc1[mt][nt] = __builtin_amdgcn_mfma_f32_16x16x32_f16(A0l[mt], bh0, acc1[mt][nt], 0,0,0);
            accM[mt][nt] = __builtin_amdgcn_mfma_f32_16x16x32_f16(A0h[mt], bl0, accM[mt][nt], 0,0,0);
            acc1[mt][nt] = __builtin_amdgcn_mfma_f32_16x16x32_f16(A1h[mt], bh1, acc1[mt][nt], 0,0,0);
            acc1[mt][nt] = __builtin_amdgcn_mfma_f32_16x16x32_f16(A1l[mt], bh1, acc1[mt][nt], 0,0,0);
            accM[mt][nt] = __builtin_amdgcn_mfma_f32_16x16x32_f16(A1h[mt], bl1, accM[mt][nt], 0,0,0);
          }
        }
      }
    }
    __syncthreads();   // S3
    #pragma unroll
    for (int mt = 0; mt < 2; ++mt)
      #pragma unroll
      for (int r = 0; r < 4; ++r){
        float gi = acc1[mt][0][r] + accM[mt][0][r]*s1m[0];
        float gf = acc1[mt][1][r] + accM[mt][1][r]*s1m[1];
        float gg = acc1[mt][2][r] + accM[mt][2][r]*s1m[2];
        float go = acc1[mt][3][r] + accM[mt][3][r]*s1m[3];
        float c = sigf(gf)*c1[mt][r] + sigf(gi)*tanhf(gg);
        float h = sigf(go)*tanhf(c);
        c1[mt][r] = c;
        h1p[(mt*16 + lq*4 + r)*132 + u] = packhl(h);
      }

    if (t >= 64){
      __syncthreads(); // S4
      // fc1: mid = lrelu(h1 @ fc1_w^T + b)
      f32x4 fa[2], faL[2];
      #pragma unroll
      for (int mt = 0; mt < 2; ++mt){
        f32x4 a; a[0]=fb;a[1]=fb;a[2]=fb;a[3]=fb; fa[mt]=a;
        f32x4 z = {0.f,0.f,0.f,0.f}; faL[mt]=z;
      }
      #pragma unroll
      for (int ks2 = 0; ks2 < 2; ++ks2){
        uint4 LV = *(const uint4*)(wsB + LB_FC1 + ((size_t)(w*2 + ks2)*64 + (size_t)l)*16);
        half8 blp[2] = { dec8i(LV.x, LV.y), dec8i(LV.z, LV.w) };
        #pragma unroll
        for (int kk = 0; kk < 2; ++kk){
          int ks = ks2*2 + kk;
          half8 Ah[2], Al[2];
          #pragma unroll
          for (int mt = 0; mt < 2; ++mt){
            const uint32_t* pp = &h1p[(mt*16+lm)*132 + ks*32 + lq*8];
            unpackA(*(const uint4*)pp, *(const uint4*)(pp+4), Ah[mt], Al[mt]);
          }
          int ci = (w*4 + ks)*64 + l;
          half8 bh = F1h[ci];
          half8 bl = blp[kk];
          #pragma unroll
          for (int mt = 0; mt < 2; ++mt){
            fa[mt]  = __builtin_amdgcn_mfma_f32_16x16x32_f16(Ah[mt], bh, fa[mt], 0,0,0);
            fa[mt]  = __builtin_amdgcn_mfma_f32_16x16x32_f16(Al[mt], bh, fa[mt], 0,0,0);
            faL[mt] = __builtin_amdgcn_mfma_f32_16x16x32_f16(Ah[mt], bl, faL[mt], 0,0,0);
          }
        }
      }
      #pragma unroll
      for (int mt = 0; mt < 2; ++mt)
        #pragma unroll
        for (int r = 0; r < 4; ++r)
          midD[(mt*16 + lq*4 + r)*132 + u] = lrelu(fa[mt][r] + faL[mt][r]*sfm);
      __syncthreads(); // S5
      {
        int m = tid >> 4, jg = tid & 15, j0 = jg*8;
        float4 wa = *(const float4*)(fc2_w + j0);
        float4 wb = *(const float4*)(fc2_w + j0 + 4);
        const float* mp = &midD[m*132 + j0];
        float4 ma = *(const float4*)mp, mb = *(const float4*)(mp+4);
        float sum = wa.x*ma.x + wa.y*ma.y + wa.z*ma.z + wa.w*ma.w
                  + wb.x*mb.x + wb.y*mb.y + wb.z*mb.z + wb.w*mb.w;
        sum += __shfl_xor(sum, 1, 16);
        sum += __shfl_xor(sum, 2, 16);
        sum += __shfl_xor(sum, 4, 16);
        sum += __shfl_xor(sum, 8, 16);
        if (jg == 0){
          float pred = sum + fc2_b[0];
          s_pred[m] = pred;
          s_res[m][t-64] = pred;
        }
      }
      __syncthreads(); // S6
    }
  }

  // ---- final combine ----
  {
    int s = tid >> 4, d = tid & 15;
    float g = s_gate[s][d];
    out[(size_t)blockIdx.x*512 + tid] = g*s_res[s][d] + (1.f - g)*s_rec[s][d];
  }
}

extern "C" void kernel_launch(void* const* d_in, const int* in_sizes, int n_in,
                              void* d_out, int out_size, void* d_ws, size_t ws_size,
                              hipStream_t stream){
  const float* data =(const float*)d_in[0];
  const float* tf   =(const float*)d_in[1];
  const float* q_w  =(const float*)d_in[2];  const float* q_b  =(const float*)d_in[3];
  const float* k_w  =(const float*)d_in[4];  const float* k_b  =(const float*)d_in[5];
  const float* v_w  =(const float*)d_in[6];  const float* v_b  =(const float*)d_in[7];
  const float* tp1_w=(const float*)d_in[8];  const float* tp1_b=(const float*)d_in[9];
  const float* tp2_w=(const float*)d_in[10]; const float* tp2_b=(const float*)d_in[11];
  const float* g1_w =(const float*)d_in[12]; const float* g1_b =(const float*)d_in[13];
  const float* g2_w =(const float*)d_in[14]; const float* g2_b =(const float*)d_in[15];
  const float* w_ih0=(const float*)d_in[16]; const float* b_ih0=(const float*)d_in[17];
  const float* w_hh0=(const float*)d_in[18]; const float* b_hh0=(const float*)d_in[19];
  const float* w_ih1=(const float*)d_in[20]; const float* b_ih1=(const float*)d_in[21];
  const float* w_hh1=(const float*)d_in[22]; const float* b_hh1=(const float*)d_in[23];
  const float* fc1_w=(const float*)d_in[24]; const float* fc1_b=(const float*)d_in[25];
  const float* fc2_w=(const float*)d_in[26]; const float* fc2_b=(const float*)d_in[27];
  float* out=(float*)d_out;
  uint8_t* wsB = (uint8_t*)d_ws;

  convert_scales<<<5,256,0,stream>>>(w_hh0, w_ih1, w_hh1, fc1_w, wsB);
  convert_w<<<232,256,0,stream>>>(w_hh0, w_ih1, w_hh1, fc1_w, tp1_w, wsB);
  mkty_main<<<256,512,0,stream>>>(data, tf, q_w,q_b, k_w,k_b, v_w,v_b,
                                  tp1_b, tp2_w,tp2_b, g1_w,g1_b, g2_w,g2_b,
                                  w_ih0,b_ih0,b_hh0, b_ih1,b_hh1,
                                  fc1_b, fc2_w,fc2_b, wsB, out);
}

// Round 7
// 2482.306 us; speedup vs baseline: 1.3812x; 1.3812x over previous
//
#include <hip/hip_runtime.h>
#include <hip/hip_fp16.h>
#include <math.h>

typedef _Float16 half8 __attribute__((ext_vector_type(8)));
typedef float f32x4 __attribute__((ext_vector_type(4)));

#define W0F 0.09817477042468103f   // 2*pi/64
#define CPY 851968u                // bytes per replicated LSTM-weight copy

__device__ __forceinline__ float sigf(float x){ return 1.f/(1.f+expf(-x)); }
__device__ __forceinline__ float lrelu(float x){ return (x>0.f)? x : 0.01f*x; }

__device__ __forceinline__ uint32_t packhl(float x){
  __half h = __float2half(x);
  __half l = __float2half(x - __half2float(h));
  return (uint32_t)__half_as_ushort(h) | ((uint32_t)__half_as_ushort(l) << 16);
}

__device__ __forceinline__ void unpackA(const uint4 d0, const uint4 d1, half8& hi, half8& lo){
  union { half8 h; uint32_t u[4]; } H, L;
  H.u[0] = (d0.x & 0xffffu) | (d0.y << 16);
  H.u[1] = (d0.z & 0xffffu) | (d0.w << 16);
  H.u[2] = (d1.x & 0xffffu) | (d1.y << 16);
  H.u[3] = (d1.z & 0xffffu) | (d1.w << 16);
  L.u[0] = (d0.x >> 16) | (d0.y & 0xffff0000u);
  L.u[1] = (d0.z >> 16) | (d0.w & 0xffff0000u);
  L.u[2] = (d1.x >> 16) | (d1.y & 0xffff0000u);
  L.u[3] = (d1.z >> 16) | (d1.w & 0xffff0000u);
  hi = H.h; lo = L.h;
}

// split-f16 3-pass fp32-accurate MFMA
__device__ __forceinline__ f32x4 mfma3(half8 ah, half8 al, half8 bh, half8 bl, f32x4 c){
  c = __builtin_amdgcn_mfma_f32_16x16x32_f16(ah, bh, c, 0,0,0);
  c = __builtin_amdgcn_mfma_f32_16x16x32_f16(al, bh, c, 0,0,0);
  c = __builtin_amdgcn_mfma_f32_16x16x32_f16(ah, bl, c, 0,0,0);
  return c;
}

// ---- ws layout (bytes), per LSTM copy (stride CPY, rep copies):
//   WH0 hi@0       lo@131072
//   WI1 hi@262144  lo@393216
//   WH1 hi@524288  lo@655360
//   FC1 hi@786432  lo@819200     (copy size 851968)
// TP1 (single copy, streamed once): hi@rep*CPY, lo@rep*CPY+524288
__global__ __launch_bounds__(256) void convert_w(
    const float* __restrict__ w_hh0, const float* __restrict__ w_ih1,
    const float* __restrict__ w_hh1, const float* __restrict__ fc1_w,
    const float* __restrict__ tp1_w, uint8_t* __restrict__ wsB, int rep)
{
  int c = blockIdx.x*256 + threadIdx.x;   // 59392 chunks of 8 elems
  const float* src; int q, K; uint32_t mb, losz = 131072u; bool isTP1 = false;
  if      (c < 8192) { src=w_hh0; q=c;        K=128;  mb=0u; }
  else if (c < 16384){ src=w_ih1; q=c-8192;   K=128;  mb=262144u; }
  else if (c < 24576){ src=w_hh1; q=c-16384;  K=128;  mb=524288u; }
  else if (c < 26624){ src=fc1_w; q=c-24576;  K=128;  mb=786432u; losz=32768u; }
  else               { src=tp1_w; q=c-26624;  K=1024; mb=0u; isTP1=true; }
  int ksb  = K >> 5;
  int lane = q & 63;
  int tks  = q >> 6;
  int tile = tks / ksb, ks = tks % ksb;
  int n = tile*16 + (lane & 15);
  int k = ks*32 + (lane >> 4)*8;
  float4 a = *(const float4*)(src + (size_t)n*K + k);
  float4 b = *(const float4*)(src + (size_t)n*K + k + 4);
  float vv[8] = {a.x,a.y,a.z,a.w,b.x,b.y,b.z,b.w};
  union { uint4 u; unsigned short s[8]; } HI, LO;
  #pragma unroll
  for (int j = 0; j < 8; ++j){
    __half hh = __float2half(vv[j]);
    HI.s[j] = __half_as_ushort(hh);
    LO.s[j] = __half_as_ushort(__float2half(vv[j] - __half2float(hh)));
  }
  if (isTP1){
    uint32_t base = (uint32_t)rep * CPY;
    *(uint4*)(wsB + base + (size_t)q*16)           = HI.u;
    *(uint4*)(wsB + base + 524288u + (size_t)q*16) = LO.u;
  } else {
    for (int r = 0; r < rep; ++r){
      uint8_t* p = wsB + (uint32_t)r*CPY + mb;
      *(uint4*)(p + (size_t)q*16)        = HI.u;
      *(uint4*)(p + losz + (size_t)q*16) = LO.u;
    }
  }
}

__global__ __launch_bounds__(512,2) void mkty_main(
    const float* __restrict__ data, const float* __restrict__ text_feature,
    const float* __restrict__ q_w, const float* __restrict__ q_b,
    const float* __restrict__ k_w, const float* __restrict__ k_b,
    const float* __restrict__ v_w, const float* __restrict__ v_b,
    const float* __restrict__ tp1_b,
    const float* __restrict__ tp2_w, const float* __restrict__ tp2_b,
    const float* __restrict__ g1_w, const float* __restrict__ g1_b,
    const float* __restrict__ g2_w, const float* __restrict__ g2_b,
    const float* __restrict__ w_ih0, const float* __restrict__ b_ih0,
    const float* __restrict__ b_hh0,
    const float* __restrict__ b_ih1, const float* __restrict__ b_hh1,
    const float* __restrict__ fc1_b,
    const float* __restrict__ fc2_w, const float* __restrict__ fc2_b,
    const uint8_t* __restrict__ wsB, int repMask, uint32_t tp1off,
    float* __restrict__ out)
{
  __shared__ float s_x[32][64];
  __shared__ float s_gate[32][16];
  __shared__ float s_rec[32][16];
  __shared__ float s_res[32][16];
  __shared__ float s_pred[32];
  __shared__ float ctab[64], stab[64];
  __shared__ __align__(16) unsigned char bufBig[33792];
  __shared__ __align__(16) unsigned char bufMed[16896];

  const int tid = threadIdx.x;
  const int w = tid >> 6, l = tid & 63;
  const int lm = l & 15, lq = l >> 4;
  const int s0blk = blockIdx.x * 32;

  {
    int f=tid*4, s=f>>6, j=f&63;
    *reinterpret_cast<float4*>(&s_x[s][j]) =
      *reinterpret_cast<const float4*>(data + (size_t)(s0blk+s)*64 + j);
  }
  if (tid<64){
    float sv,cv;
    sincosf((float)tid * W0F, &sv, &cv);
    stab[tid] = (tid==32) ? 0.f : sv;
    ctab[tid] = cv;
  }
  __syncthreads();

  // ================= Phase A: h256 = lrelu(tf @ tp1_w^T + b1)  (MFMA) =================
  {
    float* h256 = (float*)bufBig;            // [32][260]
    uint32_t* tfp = (uint32_t*)bufMed;       // [32][68] packed hi/lo
    const half8* T1h = (const half8*)(wsB + tp1off);
    const half8* T1l = (const half8*)(wsB + tp1off + 524288u);
    const int t0 = 2*w;
    f32x4 acc[2][2];
    #pragma unroll
    for (int mt=0; mt<2; ++mt)
      #pragma unroll
      for (int nt=0; nt<2; ++nt){ f32x4 z = {0.f,0.f,0.f,0.f}; acc[mt][nt] = z; }
    for (int kc = 0; kc < 1024; kc += 64){
      __syncthreads();
      { int s = tid >> 4, j0=(tid&15)*4;
        float4 v = *(const float4*)(text_feature + (size_t)(s0blk+s)*1024 + kc + j0);
        uint4 p; p.x = packhl(v.x); p.y = packhl(v.y); p.z = packhl(v.z); p.w = packhl(v.w);
        *(uint4*)&tfp[s*68 + j0] = p; }
      __syncthreads();
      #pragma unroll
      for (int ks = 0; ks < 2; ++ks){
        half8 Ah[2], Al[2];
        #pragma unroll
        for (int mt = 0; mt < 2; ++mt){
          const uint32_t* pp = &tfp[(mt*16+lm)*68 + ks*32 + lq*8];
          unpackA(*(const uint4*)pp, *(const uint4*)(pp+4), Ah[mt], Al[mt]);
        }
        int ksg = (kc >> 5) + ks;
        #pragma unroll
        for (int nt = 0; nt < 2; ++nt){
          int ci = ((t0+nt)*32 + ksg)*64 + l;
          half8 bh = T1h[ci], bl = T1l[ci];
          #pragma unroll
          for (int mt = 0; mt < 2; ++mt)
            acc[mt][nt] = mfma3(Ah[mt],Al[mt],bh,bl,acc[mt][nt]);
        }
      }
    }
    __syncthreads();
    #pragma unroll
    for (int nt = 0; nt < 2; ++nt){
      int n = (t0+nt)*16 + lm;
      float bb = tp1_b[n];
      #pragma unroll
      for (int mt = 0; mt < 2; ++mt)
        #pragma unroll
        for (int r = 0; r < 4; ++r)
          h256[(mt*16 + lq*4 + r)*260 + n] = lrelu(acc[mt][nt][r] + bb);
    }
  }
  __syncthreads();

  // ================= Phase B: tp = h256 @ tp2_w^T + b2 =================
  {
    const float* h256 = (const float*)bufBig;
    int o = tid & 127, soct = tid >> 7, ss = soct*8;
    float acc8[8];
    #pragma unroll
    for (int i=0;i<8;++i) acc8[i]=0.f;
    const float4* w2r = (const float4*)(tp2_w + o*256);
    #pragma unroll 4
    for (int k4 = 0; k4 < 64; ++k4){
      float4 w4 = w2r[k4];
      #pragma unroll
      for (int i = 0; i < 8; ++i){
        float4 hv = *(const float4*)&h256[(ss+i)*260 + k4*4];
        acc8[i] += w4.x*hv.x; acc8[i] += w4.y*hv.y;
        acc8[i] += w4.z*hv.z; acc8[i] += w4.w*hv.w;
      }
    }
    __syncthreads();
    float* tpT = (float*)bufMed;     // [32][128]
    float bb = tp2_b[o];
    #pragma unroll
    for (int i=0;i<8;++i) tpT[(ss+i)*128 + o] = acc8[i] + bb;
  }
  __syncthreads();

  // ================= Phase C: DFT -> featT[64][32] =================
  {
    float* featT = (float*)bufBig;
    #pragma unroll
    for (int i = 0; i < 2; ++i){
      int task = tid + 512*i;
      int s = task >> 5;
      int k = (task & 31) + 1;
      float re = 0.f, im = 0.f;
      #pragma unroll 8
      for (int n = 0; n < 64; ++n){
        float d = s_x[s][n];
        int m = (k*n) & 63;
        re += d*ctab[m]; im -= d*stab[m];
      }
      if (k == 32) im = 0.f;
      featT[(k-1)*32 + s] = sqrtf(re*re + im*im);
      featT[(31+k)*32 + s] = atan2f(im, re);
    }
  }
  __syncthreads();

  // ================= Phase D: Q,K,V ; QK = Q*K =================
  {
    const float* featT = (const float*)bufBig;
    const float* tpT = (const float*)bufMed;
    float* QK = (float*)(bufBig + 8192);
    float* V  = (float*)(bufBig + 16384);
    #pragma unroll
    for (int i = 0; i < 4; ++i){
      int task = tid + 512*i;
      int s = task >> 6, o = task & 63;
      float q = q_b[o];
      const float* qwr = q_w + o*64;
      #pragma unroll 4
      for (int k = 0; k < 64; ++k) q += qwr[k]*featT[k*32 + s];
      float kk = k_b[o];
      const float* kwr = k_w + o*128;
      const float* tps = tpT + s*128;
      #pragma unroll 4
      for (int k = 0; k < 128; ++k) kk += kwr[k]*tps[k];
      float vv = v_b[o];
      const float* vwr = v_w + o*128;
      #pragma unroll 4
      for (int k = 0; k < 128; ++k) vv += vwr[k]*tps[k];
      QK[s*64+o] = q*kk; V[s*64+o] = vv;
    }
  }
  __syncthreads();

  // ================= Phase E: adj = softmax(QK)*V =================
  if (tid < 32){
    float* QK = (float*)(bufBig + 8192);
    const float* V = (const float*)(bufBig + 16384);
    float mx = -1e30f;
    for (int o = 0; o < 64; ++o) mx = fmaxf(mx, QK[tid*64+o]);
    float sum = 0.f;
    for (int o = 0; o < 64; ++o){ float e = expf(QK[tid*64+o]-mx); QK[tid*64+o] = e; sum += e; }
    float inv = 1.f/sum;
    for (int o = 0; o < 64; ++o) QK[tid*64+o] *= inv*V[tid*64+o];
  }
  __syncthreads();

  // ================= Phase F: mid = lrelu(adj @ g1_w^T + b) =================
  {
    const float* ADJ = (const float*)(bufBig + 8192);
    float* midT = (float*)bufMed;    // [32][128]
    int j = tid & 127, soct = tid >> 7, ss = soct*8;
    float accm[8];
    float bb = g1_b[j];
    #pragma unroll
    for (int i=0;i<8;++i) accm[i]=bb;
    const float* wr = g1_w + j*64;
    #pragma unroll 4
    for (int k = 0; k < 64; ++k){
      float ww = wr[k];
      #pragma unroll
      for (int i=0;i<8;++i) accm[i] += ww*ADJ[(ss+i)*64 + k];
    }
    #pragma unroll
    for (int i=0;i<8;++i) midT[(ss+i)*128 + j] = lrelu(accm[i]);
  }
  __syncthreads();

  // ================= Phase G: gate + recon =================
  {
    int s = tid >> 4, o = tid & 15;
    const float* midT = (const float*)bufMed;
    const float* ADJ = (const float*)(bufBig + 8192);
    float acc = g2_b[o];
    const float* wr = g2_w + o*128;
    #pragma unroll 4
    for (int k = 0; k < 128; ++k) acc += wr[k]*midT[s*128 + k];
    float gate = sigf(acc);
    float sum = 0.f;
    float a32 = ADJ[s*64+31], p32 = ADJ[s*64+63];
    #pragma unroll
    for (int k = 1; k < 32; ++k){
      float amp = ADJ[s*64 + k-1];
      float ph  = ADJ[s*64 + 31+k];
      int m = (k*o) & 63;
      sum += amp*cosf(ph + (float)m*W0F);
    }
    float parity = (o&1)? -1.f : 1.f;
    s_gate[s][o] = gate;
    s_rec[s][o] = (2.f*sum + parity*a32*cosf(p32))*(1.f/64.f);
  }
  __syncthreads();

  // ================= LSTM (split-f16 MFMA, XCD-replicated weights) =================
  { uint32_t* hp = (uint32_t*)bufBig;
    for (int i = tid; i < 8448; i += 512) hp[i] = 0; }
  if (tid < 32) s_pred[tid] = s_x[tid][63];

  float c0[2][4] = {{0.f,0.f,0.f,0.f},{0.f,0.f,0.f,0.f}};
  float c1[2][4] = {{0.f,0.f,0.f,0.f},{0.f,0.f,0.f,0.f}};
  const int u = 16*w + lm;
  float bias0[4], wx0[4], bias1[4];
  #pragma unroll
  for (int T = 0; T < 4; ++T){
    int n = T*128 + u;
    bias0[T] = b_ih0[n] + b_hh0[n];
    wx0[T]   = w_ih0[n];
    bias1[T] = b_ih1[n] + b_hh1[n];
  }
  const float fb = fc1_b[u];
  const uint8_t* wsL = wsB + (uint32_t)(blockIdx.x & repMask) * CPY;
  const half8* WH0h = (const half8*)(wsL);
  const half8* WH0l = (const half8*)(wsL + 131072u);
  const half8* WI1h = (const half8*)(wsL + 262144u);
  const half8* WI1l = (const half8*)(wsL + 393216u);
  const half8* WH1h = (const half8*)(wsL + 524288u);
  const half8* WH1l = (const half8*)(wsL + 655360u);
  const half8* F1h  = (const half8*)(wsL + 786432u);
  const half8* F1l  = (const half8*)(wsL + 819200u);
  uint32_t* h0p = (uint32_t*)bufBig;             // [32][132]
  uint32_t* h1p = (uint32_t*)(bufBig + 16896);   // [32][132]
  float* midD = (float*)bufMed;                  // [32][132] f32 (decode)
  const int cbase = w*256 + l;
  __syncthreads();

  for (int t = 0; t < 80; ++t){
    // ---- GEMM0: gates0 = h0 @ WH0^T + x*w_ih0 + b ----
    float xv[2][4];
    #pragma unroll
    for (int mt = 0; mt < 2; ++mt)
      #pragma unroll
      for (int r = 0; r < 4; ++r){
        int m = mt*16 + lq*4 + r;
        xv[mt][r] = (t < 64) ? s_x[m][t] : s_pred[m];
      }
    f32x4 acc0[2][4];
    #pragma unroll
    for (int nt = 0; nt < 4; ++nt)
      #pragma unroll
      for (int mt = 0; mt < 2; ++mt){
        f32x4 a;
        #pragma unroll
        for (int r = 0; r < 4; ++r) a[r] = bias0[nt] + wx0[nt]*xv[mt][r];
        acc0[mt][nt] = a;
      }
    #pragma unroll
    for (int ks = 0; ks < 4; ++ks){
      half8 Ah[2], Al[2];
      #pragma unroll
      for (int mt = 0; mt < 2; ++mt){
        const uint32_t* pp = &h0p[(mt*16+lm)*132 + ks*32 + lq*8];
        unpackA(*(const uint4*)pp, *(const uint4*)(pp+4), Ah[mt], Al[mt]);
      }
      #pragma unroll
      for (int nt = 0; nt < 4; ++nt){
        int ci = nt*2048 + ks*64 + cbase;
        half8 bh = WH0h[ci], bl = WH0l[ci];
        #pragma unroll
        for (int mt = 0; mt < 2; ++mt)
          acc0[mt][nt] = mfma3(Ah[mt],Al[mt],bh,bl,acc0[mt][nt]);
      }
    }
    __syncthreads();   // S1: GEMM0 h0p reads done
    #pragma unroll
    for (int mt = 0; mt < 2; ++mt)
      #pragma unroll
      for (int r = 0; r < 4; ++r){
        float gi = acc0[mt][0][r], gf = acc0[mt][1][r];
        float gg = acc0[mt][2][r], go = acc0[mt][3][r];
        float c = sigf(gf)*c0[mt][r] + sigf(gi)*tanhf(gg);
        float h = sigf(go)*tanhf(c);
        c0[mt][r] = c;
        h0p[(mt*16 + lq*4 + r)*132 + u] = packhl(h);
      }
    __syncthreads();   // S2: new h0 visible
    // ---- GEMM1: gates1 = h0new @ WI1^T + h1 @ WH1^T + b ----
    f32x4 acc1[2][4];
    #pragma unroll
    for (int nt = 0; nt < 4; ++nt)
      #pragma unroll
      for (int mt = 0; mt < 2; ++mt){
        f32x4 a; float bb = bias1[nt];
        a[0]=bb; a[1]=bb; a[2]=bb; a[3]=bb;
        acc1[mt][nt] = a;
      }
    #pragma unroll
    for (int ks = 0; ks < 4; ++ks){
      half8 A0h[2], A0l[2], A1h[2], A1l[2];
      #pragma unroll
      for (int mt = 0; mt < 2; ++mt){
        const uint32_t* p0 = &h0p[(mt*16+lm)*132 + ks*32 + lq*8];
        unpackA(*(const uint4*)p0, *(const uint4*)(p0+4), A0h[mt], A0l[mt]);
        const uint32_t* p1 = &h1p[(mt*16+lm)*132 + ks*32 + lq*8];
        unpackA(*(const uint4*)p1, *(const uint4*)(p1+4), A1h[mt], A1l[mt]);
      }
      #pragma unroll
      for (int nt = 0; nt < 4; ++nt){
        int ci = nt*2048 + ks*64 + cbase;
        half8 bh0 = WI1h[ci], bl0 = WI1l[ci];
        half8 bh1 = WH1h[ci], bl1 = WH1l[ci];
        #pragma unroll
        for (int mt = 0; mt < 2; ++mt){
          acc1[mt][nt] = mfma3(A0h[mt],A0l[mt],bh0,bl0,acc1[mt][nt]);
          acc1[mt][nt] = mfma3(A1h[mt],A1l[mt],bh1,bl1,acc1[mt][nt]);
        }
      }
    }
    __syncthreads();   // S3: GEMM1 h1p reads done
    #pragma unroll
    for (int mt = 0; mt < 2; ++mt)
      #pragma unroll
      for (int r = 0; r < 4; ++r){
        float gi = acc1[mt][0][r], gf = acc1[mt][1][r];
        float gg = acc1[mt][2][r], go = acc1[mt][3][r];
        float c = sigf(gf)*c1[mt][r] + sigf(gi)*tanhf(gg);
        float h = sigf(go)*tanhf(c);
        c1[mt][r] = c;
        h1p[(mt*16 + lq*4 + r)*132 + u] = packhl(h);
      }

    if (t >= 64){
      __syncthreads(); // S4: new h1 visible for fc1
      // fc1: mid = lrelu(h1 @ fc1_w^T + b)
      f32x4 fa[2];
      #pragma unroll
      for (int mt = 0; mt < 2; ++mt){ f32x4 a; a[0]=fb;a[1]=fb;a[2]=fb;a[3]=fb; fa[mt]=a; }
      #pragma unroll
      for (int ks = 0; ks < 4; ++ks){
        half8 Ah[2], Al[2];
        #pragma unroll
        for (int mt = 0; mt < 2; ++mt){
          const uint32_t* pp = &h1p[(mt*16+lm)*132 + ks*32 + lq*8];
          unpackA(*(const uint4*)pp, *(const uint4*)(pp+4), Ah[mt], Al[mt]);
        }
        int ci = (w*4 + ks)*64 + l;
        half8 bh = F1h[ci], bl = F1l[ci];
        #pragma unroll
        for (int mt = 0; mt < 2; ++mt)
          fa[mt] = mfma3(Ah[mt],Al[mt],bh,bl,fa[mt]);
      }
      #pragma unroll
      for (int mt = 0; mt < 2; ++mt)
        #pragma unroll
        for (int r = 0; r < 4; ++r)
          midD[(mt*16 + lq*4 + r)*132 + u] = lrelu(fa[mt][r]);
      __syncthreads(); // S5: midD visible
      {
        int m = tid >> 4, jg = tid & 15, j0 = jg*8;
        float4 wa = *(const float4*)(fc2_w + j0);
        float4 wb = *(const float4*)(fc2_w + j0 + 4);
        const float* mp = &midD[m*132 + j0];
        float4 ma = *(const float4*)mp, mb = *(const float4*)(mp+4);
        float sum = wa.x*ma.x + wa.y*ma.y + wa.z*ma.z + wa.w*ma.w
                  + wb.x*mb.x + wb.y*mb.y + wb.z*mb.z + wb.w*mb.w;
        sum += __shfl_xor(sum, 1, 16);
        sum += __shfl_xor(sum, 2, 16);
        sum += __shfl_xor(sum, 4, 16);
        sum += __shfl_xor(sum, 8, 16);
        if (jg == 0){
          float pred = sum + fc2_b[0];
          s_pred[m] = pred;
          s_res[m][t-64] = pred;
        }
      }
      __syncthreads(); // S6: s_pred visible
    }
  }

  // ---- final combine ----
  {
    int s = tid >> 4, d = tid & 15;
    float g = s_gate[s][d];
    out[(size_t)blockIdx.x*512 + tid] = g*s_res[s][d] + (1.f - g)*s_rec[s][d];
  }
}

extern "C" void kernel_launch(void* const* d_in, const int* in_sizes, int n_in,
                              void* d_out, int out_size, void* d_ws, size_t ws_size,
                              hipStream_t stream){
  const float* data =(const float*)d_in[0];
  const float* tf   =(const float*)d_in[1];
  const float* q_w  =(const float*)d_in[2];  const float* q_b  =(const float*)d_in[3];
  const float* k_w  =(const float*)d_in[4];  const float* k_b  =(const float*)d_in[5];
  const float* v_w  =(const float*)d_in[6];  const float* v_b  =(const float*)d_in[7];
  const float* tp1_w=(const float*)d_in[8];  const float* tp1_b=(const float*)d_in[9];
  const float* tp2_w=(const float*)d_in[10]; const float* tp2_b=(const float*)d_in[11];
  const float* g1_w =(const float*)d_in[12]; const float* g1_b =(const float*)d_in[13];
  const float* g2_w =(const float*)d_in[14]; const float* g2_b =(const float*)d_in[15];
  const float* w_ih0=(const float*)d_in[16]; const float* b_ih0=(const float*)d_in[17];
  const float* w_hh0=(const float*)d_in[18]; const float* b_hh0=(const float*)d_in[19];
  const float* w_ih1=(const float*)d_in[20]; const float* b_ih1=(const float*)d_in[21];
  const float* w_hh1=(const float*)d_in[22]; const float* b_hh1=(const float*)d_in[23];
  const float* fc1_w=(const float*)d_in[24]; const float* fc1_b=(const float*)d_in[25];
  const float* fc2_w=(const float*)d_in[26]; const float* fc2_b=(const float*)d_in[27];
  float* out=(float*)d_out;
  uint8_t* wsB = (uint8_t*)d_ws;

  // 8-way XCD replication if workspace allows (8*832KB + 1MB TP1), else single copy
  int rep = (ws_size >= (size_t)8*CPY + 1048576u) ? 8 : 1;
  int repMask = rep - 1;
  uint32_t tp1off = (uint32_t)rep * CPY;

  convert_w<<<232,256,0,stream>>>(w_hh0, w_ih1, w_hh1, fc1_w, tp1_w, wsB, rep);
  mkty_main<<<256,512,0,stream>>>(data, tf, q_w,q_b, k_w,k_b, v_w,v_b,
                                  tp1_b, tp2_w,tp2_b, g1_w,g1_b, g2_w,g2_b,
                                  w_ih0,b_ih0,b_hh0, b_ih1,b_hh1,
                                  fc1_b, fc2_w,fc2_b, wsB, repMask, tp1off, out);
}